// Round 14
// baseline (294.574 us; speedup 1.0000x reference)
//
#include <hip/hip_runtime.h>

typedef unsigned short u16;
typedef __bf16 bf16x8 __attribute__((ext_vector_type(8)));
typedef float f32x4 __attribute__((ext_vector_type(4)));
typedef unsigned short u16x8 __attribute__((ext_vector_type(8)));

#define NB 64
#define NT 128
#define NA 30
#define NG 3
#define NE 64
#define NH 256
#define NN 8192     // B*T
#define SD 2520
#define KP 2560     // K padded to mult of 64
#define NC 3328     // concat first-layer cols = 13*256
#define NKT 40      // K tiles of 64
#define NITER 20    // 2 K-tiles per iteration

__device__ __forceinline__ u16 f2bf(float f) {
  union { float f; unsigned u; } c; c.f = f;
  unsigned u = c.u + 0x7FFFu + ((c.u >> 16) & 1u);
  return (u16)(u >> 16);
}
__device__ __forceinline__ float bf2f(u16 h) {
  union { unsigned u; float f; } c; c.u = ((unsigned)h) << 16;
  return c.f;
}
__device__ __forceinline__ float eluf(float x) { return x > 0.f ? x : expm1f(x); }

__device__ __forceinline__ void gload16(const u16* g, u16* l) {
  __builtin_amdgcn_global_load_lds((const __attribute__((address_space(1))) void*)g,
                                   (__attribute__((address_space(3))) void*)l, 16, 0, 0);
}

// ---------------- merged pack kernel: A + BT + w2tw1(frag) + w2ts(frag,12u) + grps(sorted)+cnt ----------------
__global__ __launch_bounds__(256) void pack_all_k(
    const float* __restrict__ states,
    const float* __restrict__ gw1W1, const float* __restrict__ gw1b1,
    const float* __restrict__ gb1W1, const float* __restrict__ gb1b1,
    const float* __restrict__ gw2W1, const float* __restrict__ gw2b1,
    const float* __restrict__ gb2W1, const float* __restrict__ gb2b1,
    const float* __restrict__ hw1W1, const float* __restrict__ hw1b1,
    const float* __restrict__ hb1W1, const float* __restrict__ hb1b1,
    const float* __restrict__ hw2W1, const float* __restrict__ hw2b1,
    const float* __restrict__ hb2W1, const float* __restrict__ hb2b1,
    const float* __restrict__ gw1W2, const float* __restrict__ gb1W2,
    const float* __restrict__ gw2W2, const float* __restrict__ hw1W2,
    const float* __restrict__ hb1W2, const float* __restrict__ hw2W2,
    const float* __restrict__ gb2W2, const float* __restrict__ hb2W2,
    u16* __restrict__ A, u16* __restrict__ BT, float* __restrict__ bias,
    u16* __restrict__ w2tw1, u16* __restrict__ w2ts,
    int* __restrict__ grps, int* __restrict__ gcnt) {
  int bid = blockIdx.x;
  if (bid < 10240) {
    // ---- pack A: bf16[n][KP] from states f32 ----
    int tid = bid * 256 + threadIdx.x;            // 8192*320 exact
    int n = tid / 320, kq = tid - n * 320;
    int k = kq * 8;
    u16x8 v;
    if (k < SD) {
      const float4* p = reinterpret_cast<const float4*>(states + (size_t)n * SD + k);
      float4 x0 = p[0], x1 = p[1];
      v[0]=f2bf(x0.x); v[1]=f2bf(x0.y); v[2]=f2bf(x0.z); v[3]=f2bf(x0.w);
      v[4]=f2bf(x1.x); v[5]=f2bf(x1.y); v[6]=f2bf(x1.z); v[7]=f2bf(x1.w);
    } else {
      v[0]=0;v[1]=0;v[2]=0;v[3]=0;v[4]=0;v[5]=0;v[6]=0;v[7]=0;
    }
    *reinterpret_cast<u16x8*>(A + (size_t)n * KP + k) = v;
  } else if (bid < 14400) {
    // ---- pack BT (+bias) ----
    int tid = (bid - 10240) * 256 + threadIdx.x;  // 320*3328 exact
    int kq = tid / NC, j = tid - kq * NC;
    const float* W; const float* bsrc; size_t cbase; int stride; int q;
    if (j < 768)        { q=j;      int g=q>>8; W=gw1W1; cbase=(size_t)g*SD*NH + (q&255); stride=NH; bsrc=gw1b1; }
    else if (j < 1536)  { q=j-768;  int g=q>>8; W=gb1W1; cbase=(size_t)g*SD*NH + (q&255); stride=NH; bsrc=gb1b1; }
    else if (j < 2304)  { q=j-1536; int g=q>>8; W=gw2W1; cbase=(size_t)g*SD*NH + (q&255); stride=NH; bsrc=gw2b1; }
    else if (j < 2496)  { q=j-2304; int g=q>>6; W=gb2W1; cbase=(size_t)g*SD*NE + (q&63);  stride=NE; bsrc=gb2b1; }
    else if (j < 2752)  { q=j-2496; W=hw1W1; cbase=q; stride=NH; bsrc=hw1b1; }
    else if (j < 3008)  { q=j-2752; W=hb1W1; cbase=q; stride=NH; bsrc=hb1b1; }
    else if (j < 3264)  { q=j-3008; W=hw2W1; cbase=q; stride=NH; bsrc=hw2b1; }
    else                { q=j-3264; W=hb2W1; cbase=q; stride=NE; bsrc=hb2b1; }
    int k = kq * 8;
    u16x8 v;
    #pragma unroll
    for (int i = 0; i < 8; ++i) {
      int d = k + i;
      v[i] = (d < SD) ? f2bf(W[cbase + (size_t)d * stride]) : (u16)0;
    }
    *reinterpret_cast<u16x8*>(BT + (size_t)j * KP + k) = v;
    if (kq == 0) bias[j] = bsrc[q];
  } else if (bid < 15120) {
    // ---- pack w2tw1 in fragment-major order (90 slabs x 2048 threads) ----
    int tid = (bid - 14400) * 256 + threadIdx.x;  // 184320 exact
    int lane = tid & 63, cf = (tid >> 6) & 3, ks = (tid >> 8) & 7, slab = tid >> 11;
    int g = slab / 30, a = slab - g * 30;
    int e = cf * 16 + (lane & 15);
    int h0 = ks * 32 + (lane >> 4) * 8;
    const float* src = gw1W2 + (size_t)g * (NH * 1920) + (size_t)h0 * 1920 + a * 64 + e;
    u16x8 v;
    #pragma unroll
    for (int i = 0; i < 8; ++i) v[i] = f2bf(src[(size_t)i * 1920]);
    *reinterpret_cast<u16x8*>(w2tw1 + (size_t)tid * 8) = v;
  } else if (bid < 15216) {
    // ---- pack w2ts in fragment-major order (12 units x 2048 threads) ----
    // unit 11: block-diag dot vectors: cols 0..2 = gb2W2 per group (K rows 0..191
    // map to act cols 2304..2495), col 3 = hb2W2 (K rows 192..255 -> act 3264..3327)
    int tid = (bid - 15120) * 256 + threadIdx.x;  // 24576 exact
    int lane = tid & 63, cf = (tid >> 6) & 3, ks = (tid >> 8) & 7, u = tid >> 11;
    int c = cf * 16 + (lane & 15);
    int h0 = ks * 32 + (lane >> 4) * 8;
    u16x8 v;
    if (u < 11) {
      const float* src; int stride;
      if (u < 3)       { src = gb1W2 + (size_t)u * (NH*NE) + (size_t)h0 * NE + c;     stride = NE; }
      else if (u < 6)  { src = gw2W2 + (size_t)(u-3) * (NH*NE) + (size_t)h0 * NE + c; stride = NE; }
      else if (u < 9)  { src = hw1W2 + (size_t)h0 * (NG*NE) + (u-6)*64 + c;           stride = NG*NE; }
      else if (u == 9) { src = hb1W2 + (size_t)h0 * NE + c;                           stride = NE; }
      else             { src = hw2W2 + (size_t)h0 * NE + c;                           stride = NE; }
      #pragma unroll
      for (int i = 0; i < 8; ++i) v[i] = f2bf(src[(size_t)i * stride]);
    } else {
      #pragma unroll
      for (int i = 0; i < 8; ++i) {
        int k = h0 + i;
        float val = 0.f;
        if (ks < 6) { if (c == k / 64) val = gb2W2[k]; }
        else        { int kk = k - 192; if (c == 3) val = hb2W2[kk]; }
        v[i] = f2bf(val);
      }
    }
    *reinterpret_cast<u16x8*>(w2ts + (size_t)tid * 8) = v;
  } else {
    // ---- grps: per-b counting sort of agents by group; entry = a; cnt table ----
    int b = threadIdx.x;
    if (b >= NB) return;
    int gv0 = 0, gv1 = 0;
    int cnt0 = 0, cnt1 = 0, cnt2 = 0;
    #pragma unroll
    for (int a = 0; a < NA; ++a) {
      int g = 0;
      #pragma unroll
      for (int gi = 0; gi < NG; ++gi)
        if (states[(size_t)b * NT * SD + a * 32 + 29 + gi] == 1.0f) g = gi;
      if (a < 15) gv0 |= g << (2 * a); else gv1 |= g << (2 * (a - 15));
      if (g == 0) ++cnt0; else if (g == 1) ++cnt1; else ++cnt2;
    }
    gcnt[b * 4 + 0] = cnt0; gcnt[b * 4 + 1] = cnt1; gcnt[b * 4 + 2] = cnt2;
    int off0 = 0, off1 = cnt0, off2 = cnt0 + cnt1;
    #pragma unroll
    for (int a = 0; a < NA; ++a) {
      int g = (a < 15) ? ((gv0 >> (2 * a)) & 3) : ((gv1 >> (2 * (a - 15))) & 3);
      int pos;
      if (g == 0) pos = off0++; else if (g == 1) pos = off1++; else pos = off2++;
      grps[b * NA + pos] = a;
    }
  }
}

// ---------------- big concat GEMM: act = relu(A @ BT^T + bias) ----------------
// m201-style 8-phase schedule (R7, best measured): 256x256 tile, BK=64, 8 waves
// (2Mx4N), 2 dbufs x 4 half-tile slots. vmcnt(4) at phases 4/8 only.
__global__ __launch_bounds__(512, 2) void gemm1_k(const u16* __restrict__ A, const u16* __restrict__ BT,
    const float* __restrict__ bias, u16* __restrict__ act) {
  __shared__ u16 lds[65536];          // 2 bufs x (Aa,Ab,Ba,Bb) x 16 KB = 128 KB
  int t = threadIdx.x;
  int wg = blockIdx.x;                // 416 = 32 x 13, 416 % 8 == 0
  int swz = (wg & 7) * 52 + (wg >> 3);
  int by = swz / 13, bx = swz - by * 13;
  size_t mb = (size_t)by * 256, nb = (size_t)bx * 256;
  int lane = t & 63, w = t >> 6;
  int wm = (w >> 2) * 128;            // 2 M-waves
  int wn = (w & 3) * 64;              // 4 N-waves
  int l15 = lane & 15, hi = lane >> 4;

  int srow = t >> 3;                                    // 0..63
  int scol = (((t & 7) ^ (srow & 7)) << 3);             // swizzled source col (elems)
  const u16* aS = A + (mb + srow) * KP + scol;
  const u16* bS = BT + (nb + srow) * KP + scol;

#define STGA(buf, h, kt) { \
    u16* d_ = lds + (buf) * 32768 + (h) * 8192; \
    const u16* s_ = aS + (size_t)((h) * 128) * KP + (size_t)(kt) * 64; \
    gload16(s_,                  d_ + t * 8); \
    gload16(s_ + (size_t)64 * KP, d_ + 4096 + t * 8); }
#define STGB(buf, h, kt) { \
    u16* d_ = lds + (buf) * 32768 + 16384 + (h) * 8192; \
    const u16* s_ = bS + (size_t)((h) * 128) * KP + (size_t)(kt) * 64; \
    gload16(s_,                  d_ + t * 8); \
    gload16(s_ + (size_t)64 * KP, d_ + 4096 + t * 8); }

  f32x4 acc[8][4];
  #pragma unroll
  for (int mi = 0; mi < 8; ++mi)
    #pragma unroll
    for (int ni = 0; ni < 4; ++ni) acc[mi][ni] = {0.f, 0.f, 0.f, 0.f};

  const char* A0 = (const char*)(lds) + (wm ? 16384 : 0);
  const char* B0 = (const char*)(lds) + 32768 + ((wn & 128) ? 16384 : 0);
  const char* A1 = A0 + 65536;
  const char* B1 = B0 + 65536;
  int rx = l15 & 7;
  int aBase = l15 * 128;
  int bBase = ((wn & 64) + l15) * 128;
  int slot0 = (hi ^ rx) << 4;
  int slot1 = ((4 + hi) ^ rx) << 4;

  bf16x8 afA[4][2], afB[4][2], bfA[2][2], bfB[2][2];

#define LD_AFA(Ab) { _Pragma("unroll") for (int m_ = 0; m_ < 4; ++m_) { \
    afA[m_][0] = *reinterpret_cast<const bf16x8*>((Ab) + aBase + m_ * 2048 + slot0); \
    afA[m_][1] = *reinterpret_cast<const bf16x8*>((Ab) + aBase + m_ * 2048 + slot1); } }
#define LD_AFB(Ab) { _Pragma("unroll") for (int m_ = 0; m_ < 4; ++m_) { \
    afB[m_][0] = *reinterpret_cast<const bf16x8*>((Ab) + aBase + (4 + m_) * 2048 + slot0); \
    afB[m_][1] = *reinterpret_cast<const bf16x8*>((Ab) + aBase + (4 + m_) * 2048 + slot1); } }
#define LD_BFA(Bb) { _Pragma("unroll") for (int n_ = 0; n_ < 2; ++n_) { \
    bfA[n_][0] = *reinterpret_cast<const bf16x8*>((Bb) + bBase + n_ * 2048 + slot0); \
    bfA[n_][1] = *reinterpret_cast<const bf16x8*>((Bb) + bBase + n_ * 2048 + slot1); } }
#define LD_BFB(Bb) { _Pragma("unroll") for (int n_ = 0; n_ < 2; ++n_) { \
    bfB[n_][0] = *reinterpret_cast<const bf16x8*>((Bb) + bBase + (2 + n_) * 2048 + slot0); \
    bfB[n_][1] = *reinterpret_cast<const bf16x8*>((Bb) + bBase + (2 + n_) * 2048 + slot1); } }
#define MM_Q(AF, BF, MO, NO) { _Pragma("unroll") for (int m_ = 0; m_ < 4; ++m_) \
    _Pragma("unroll") for (int n_ = 0; n_ < 2; ++n_) { \
      acc[(MO)+m_][(NO)+n_] = __builtin_amdgcn_mfma_f32_16x16x32_bf16(AF[m_][0], BF[n_][0], acc[(MO)+m_][(NO)+n_], 0, 0, 0); \
      acc[(MO)+m_][(NO)+n_] = __builtin_amdgcn_mfma_f32_16x16x32_bf16(AF[m_][1], BF[n_][1], acc[(MO)+m_][(NO)+n_], 0, 0, 0); } }
#define SYNC_IN  __builtin_amdgcn_s_barrier(); \
                 asm volatile("s_waitcnt lgkmcnt(0)" ::: "memory"); \
                 __builtin_amdgcn_sched_barrier(0); \
                 __builtin_amdgcn_s_setprio(1);
#define SYNC_OUT __builtin_amdgcn_s_setprio(0); \
                 __builtin_amdgcn_s_barrier(); \
                 asm volatile("" ::: "memory");

  STGA(0, 0, 0); STGA(0, 1, 0); STGB(0, 0, 0); STGB(0, 1, 0);
  STGB(1, 0, 1); STGB(1, 1, 1);
  asm volatile("s_waitcnt vmcnt(4)" ::: "memory");
  __builtin_amdgcn_s_barrier();
  asm volatile("" ::: "memory");

  for (int it = 0; it < NITER; ++it) {
    int k1 = 2 * it + 1;
    bool t2 = (2 * it + 2 < NKT), t3 = (2 * it + 3 < NKT);
    LD_AFA(A0); LD_BFA(B0);
    STGA(1, 0, k1);
    SYNC_IN; MM_Q(afA, bfA, 0, 0); SYNC_OUT;
    LD_BFB(B0);
    STGA(1, 1, k1);
    SYNC_IN; MM_Q(afA, bfB, 0, 2); SYNC_OUT;
    LD_AFB(A0);
    if (t2) STGB(0, 0, 2 * it + 2);
    SYNC_IN; MM_Q(afB, bfB, 4, 2); SYNC_OUT;
    if (t2) STGB(0, 1, 2 * it + 2);
    __builtin_amdgcn_s_barrier();
    __builtin_amdgcn_s_setprio(1); MM_Q(afB, bfA, 4, 0); __builtin_amdgcn_s_setprio(0);
    if (it == NITER - 1) { asm volatile("s_waitcnt vmcnt(0)" ::: "memory"); }
    else                 { asm volatile("s_waitcnt vmcnt(4)" ::: "memory"); }
    __builtin_amdgcn_s_barrier();
    asm volatile("" ::: "memory");
    LD_AFA(A1); LD_BFA(B1);
    if (t2) STGA(0, 0, 2 * it + 2);
    SYNC_IN; MM_Q(afA, bfA, 0, 0); SYNC_OUT;
    LD_BFB(B1);
    if (t2) STGA(0, 1, 2 * it + 2);
    SYNC_IN; MM_Q(afA, bfB, 0, 2); SYNC_OUT;
    LD_AFB(A1);
    if (t3) STGB(1, 0, 2 * it + 3);
    SYNC_IN; MM_Q(afB, bfB, 4, 2); SYNC_OUT;
    if (t3) STGB(1, 1, 2 * it + 3);
    __builtin_amdgcn_s_barrier();
    __builtin_amdgcn_s_setprio(1); MM_Q(afB, bfA, 4, 0); __builtin_amdgcn_s_setprio(0);
    if (t3) { asm volatile("s_waitcnt vmcnt(4)" ::: "memory"); }
    __builtin_amdgcn_s_barrier();
    asm volatile("" ::: "memory");
  }

  int r00 = (int)mb + wm + hi * 4;
  int cc0 = (int)nb + wn + l15;
  float bv0 = bias[cc0], bv1 = bias[cc0 + 16], bv2 = bias[cc0 + 32], bv3 = bias[cc0 + 48];
  #pragma unroll
  for (int mi = 0; mi < 8; ++mi) {
    #pragma unroll
    for (int i = 0; i < 4; ++i) {
      u16* dst = act + (size_t)(r00 + mi * 16 + i) * NC + cc0;
      float v0 = acc[mi][0][i] + bv0; v0 = v0 > 0.f ? v0 : 0.f;
      float v1 = acc[mi][1][i] + bv1; v1 = v1 > 0.f ? v1 : 0.f;
      float v2 = acc[mi][2][i] + bv2; v2 = v2 > 0.f ? v2 : 0.f;
      float v3 = acc[mi][3][i] + bv3; v3 = v3 > 0.f ? v3 : 0.f;
      dst[0] = f2bf(v0); dst[16] = f2bf(v1); dst[32] = f2bf(v2); dst[48] = f2bf(v3);
    }
  }
#undef STGA
#undef STGB
#undef LD_AFA
#undef LD_AFB
#undef LD_BFA
#undef LD_BFB
#undef MM_Q
#undef SYNC_IN
#undef SYNC_OUT
}

// ---------------- masked w1 second layer + q-weighted group accumulate ----------------
// one block per (32 rows, group); af loaded once; disjoint qw1acc[g] slices.
__global__ __launch_bounds__(128) void c1a_k(const u16* __restrict__ act, const float* __restrict__ qvals,
    const int* __restrict__ grps, const int* __restrict__ gcnt, const u16* __restrict__ w2tw1,
    const float* __restrict__ gw1b2, float* __restrict__ qw1acc) {
  int t = threadIdx.x, lane = t & 63, w = t >> 6;
  int rb = blockIdx.x;                  // 256 row-blocks * 32 rows
  int g = blockIdx.y;                   // 3 groups
  int nb0 = rb * 32 + w * 16;
  int b = rb >> 2;                      // uniform b per block
  int l16 = lane & 15, lk8 = (lane >> 4) * 8;
  int cnt0 = gcnt[b * 4], cnt1 = gcnt[b * 4 + 1], cnt2 = gcnt[b * 4 + 2];
  int start = (g >= 1 ? cnt0 : 0) + (g >= 2 ? cnt1 : 0);
  int cnt = (g == 0) ? cnt0 : (g == 1) ? cnt1 : cnt2;
  float gacc[4][4];
  #pragma unroll
  for (int cf = 0; cf < 4; ++cf)
    #pragma unroll
    for (int i = 0; i < 4; ++i) gacc[cf][i] = 0.f;
  const u16* arow = act + (size_t)(nb0 + l16) * NC;
  int r4 = nb0 + (lane >> 4) * 4;
  const u16* abase = arow + g * NH;
  bf16x8 af0[4], af1[4];
  #pragma unroll
  for (int ks = 0; ks < 4; ++ks) {
    af0[ks] = *reinterpret_cast<const bf16x8*>(abase + ks * 32 + lk8);
    af1[ks] = *reinterpret_cast<const bf16x8*>(abase + (4 + ks) * 32 + lk8);
  }
  const int* sl = grps + b * NA + start;
  for (int ai = 0; ai < cnt; ++ai) {
    int a = sl[ai];
    f32x4 t4[4], u4[4];
    #pragma unroll
    for (int cf = 0; cf < 4; ++cf) { t4[cf] = {0.f,0.f,0.f,0.f}; u4[cf] = {0.f,0.f,0.f,0.f}; }
    const u16* bbase = w2tw1 + (size_t)(g * NA + a) * 16384 + lane * 8;
    #pragma unroll
    for (int ks = 0; ks < 4; ++ks) {
      #pragma unroll
      for (int cf = 0; cf < 4; ++cf) {
        bf16x8 bf0 = *reinterpret_cast<const bf16x8*>(bbase + (ks * 4 + cf) * 512);
        bf16x8 bf1 = *reinterpret_cast<const bf16x8*>(bbase + ((4 + ks) * 4 + cf) * 512);
        t4[cf] = __builtin_amdgcn_mfma_f32_16x16x32_bf16(af0[ks], bf0, t4[cf], 0, 0, 0);
        u4[cf] = __builtin_amdgcn_mfma_f32_16x16x32_bf16(af1[ks], bf1, u4[cf], 0, 0, 0);
      }
    }
    float qv[4];
    #pragma unroll
    for (int i = 0; i < 4; ++i) qv[i] = qvals[(size_t)(r4 + i) * NA + a];
    const float* bias = gw1b2 + (size_t)g * (NA * NE) + a * NE;
    #pragma unroll
    for (int cf = 0; cf < 4; ++cf) {
      float bv = bias[cf*16 + l16];
      #pragma unroll
      for (int i = 0; i < 4; ++i) gacc[cf][i] += qv[i] * fabsf(t4[cf][i] + u4[cf][i] + bv);
    }
  }
  #pragma unroll
  for (int cf = 0; cf < 4; ++cf)
    #pragma unroll
    for (int i = 0; i < 4; ++i)
      qw1acc[(size_t)(r4 + i) * 192 + g * 64 + cf * 16 + l16] = gacc[cf][i];
}

// ---------------- fused second layers + final combine (c1b+c2) ----------------
// Per wave: 16 rows. 12 MFMA units from fragment-major w2ts (units 0-2 b1,
// 3-5 w2, 6-8 hw1, 9 hb1, 10 hw2, 11 block-diag dots). Combine entirely in
// fragment layout: per-16-lane-group shfl_xor reductions.
__global__ __launch_bounds__(256) void c1bc2_k(const u16* __restrict__ act,
    const float* __restrict__ qw1acc, const u16* __restrict__ w2ts,
    const float* __restrict__ gb1b2, const float* __restrict__ gw2b2, const float* __restrict__ hw1b2,
    const float* __restrict__ hb1b2, const float* __restrict__ hw2b2,
    const float* __restrict__ gb2b2, const float* __restrict__ hb2b2,
    float* __restrict__ out) {
  int t = threadIdx.x, lane = t & 63, w = t >> 6;
  int nb0 = blockIdx.x * 64 + w * 16;
  int l16 = lane & 15, hi = lane >> 4, lk8 = hi * 8;
  const u16* arow = act + (size_t)(nb0 + l16) * NC;
  int r4 = nb0 + hi * 4;

#define UNIT(u_, aoff_, res_) { \
    f32x4 t4_[4]; \
    _Pragma("unroll") for (int cf = 0; cf < 4; ++cf) t4_[cf] = {0.f,0.f,0.f,0.f}; \
    const u16* bb_ = w2ts + (size_t)(u_) * 16384 + lane * 8; \
    _Pragma("unroll") for (int ks = 0; ks < 8; ++ks) { \
      bf16x8 af_ = *reinterpret_cast<const bf16x8*>(arow + (aoff_) + ks * 32 + lk8); \
      _Pragma("unroll") for (int cf = 0; cf < 4; ++cf) { \
        bf16x8 bf_ = *reinterpret_cast<const bf16x8*>(bb_ + (ks * 4 + cf) * 512); \
        t4_[cf] = __builtin_amdgcn_mfma_f32_16x16x32_bf16(af_, bf_, t4_[cf], 0, 0, 0); \
      } } \
    _Pragma("unroll") for (int cf = 0; cf < 4; ++cf) res_[cf] = t4_[cf]; }

#define GRED(x) { x += __shfl_xor(x, 1, 64); x += __shfl_xor(x, 2, 64); \
                  x += __shfl_xor(x, 4, 64); x += __shfl_xor(x, 8, 64); }

  // ---- unit 11: four dot products (cf=0 only; 8 MFMAs) ----
  f32x4 d4 = {0.f, 0.f, 0.f, 0.f};
  {
    const u16* bb = w2ts + (size_t)11 * 16384 + lane * 8;
    #pragma unroll
    for (int ks = 0; ks < 8; ++ks) {
      int aoff = (ks < 6) ? (2304 + ks * 32) : (3264 + (ks - 6) * 32);
      bf16x8 af = *reinterpret_cast<const bf16x8*>(arow + aoff + lk8);
      bf16x8 bf = *reinterpret_cast<const bf16x8*>(bb + (ks * 4) * 512);
      d4 = __builtin_amdgcn_mfma_f32_16x16x32_bf16(af, bf, d4, 0, 0, 0);
    }
  }
  float dotn[4][4];                   // [n][i], broadcast to all lanes in group
  #pragma unroll
  for (int n = 0; n < 4; ++n)
    #pragma unroll
    for (int i = 0; i < 4; ++i)
      dotn[n][i] = __shfl(d4[i], (lane & 48) + n, 64);

  // ---- per-group: b1 (unit g), w2 (unit 3+g), qw1acc -> gq[g][i] ----
  float gq[3][4];
  #pragma unroll
  for (int g = 0; g < 3; ++g) {
    f32x4 b1r[4], w2r[4];
    UNIT(g, 768 + g * 256, b1r);
    UNIT(3 + g, 1536 + g * 256, w2r);
    float part[4] = {0.f, 0.f, 0.f, 0.f};
    #pragma unroll
    for (int cf = 0; cf < 4; ++cf) {
      float b1b = gb1b2[g * 64 + cf * 16 + l16];
      float w2b = gw2b2[g * 64 + cf * 16 + l16];
      #pragma unroll
      for (int i = 0; i < 4; ++i) {
        float q = qw1acc[(size_t)(r4 + i) * 192 + g * 64 + cf * 16 + l16];
        part[i] += eluf(q + b1r[cf][i] + b1b) * fabsf(w2r[cf][i] + w2b);
      }
    }
    #pragma unroll
    for (int i = 0; i < 4; ++i) {
      GRED(part[i]);
      gq[g][i] = part[i] + dotn[g][i] + gb2b2[g];
    }
  }

  // ---- h-side units: hw1 x3 (shared af), hb1, hw2 ----
  f32x4 h6[4], h7[4], h8[4], h9[4], h10[4];
  {
    f32x4 t6[4], t7[4], t8[4];
    #pragma unroll
    for (int cf = 0; cf < 4; ++cf) { t6[cf] = {0.f,0.f,0.f,0.f}; t7[cf] = {0.f,0.f,0.f,0.f}; t8[cf] = {0.f,0.f,0.f,0.f}; }
    const u16* bb6 = w2ts + (size_t)6 * 16384 + lane * 8;
    const u16* bb7 = w2ts + (size_t)7 * 16384 + lane * 8;
    const u16* bb8 = w2ts + (size_t)8 * 16384 + lane * 8;
    #pragma unroll
    for (int ks = 0; ks < 8; ++ks) {
      bf16x8 af = *reinterpret_cast<const bf16x8*>(arow + 2496 + ks * 32 + lk8);
      #pragma unroll
      for (int cf = 0; cf < 4; ++cf) {
        t6[cf] = __builtin_amdgcn_mfma_f32_16x16x32_bf16(af, *reinterpret_cast<const bf16x8*>(bb6 + (ks*4+cf)*512), t6[cf], 0, 0, 0);
        t7[cf] = __builtin_amdgcn_mfma_f32_16x16x32_bf16(af, *reinterpret_cast<const bf16x8*>(bb7 + (ks*4+cf)*512), t7[cf], 0, 0, 0);
        t8[cf] = __builtin_amdgcn_mfma_f32_16x16x32_bf16(af, *reinterpret_cast<const bf16x8*>(bb8 + (ks*4+cf)*512), t8[cf], 0, 0, 0);
      }
    }
    #pragma unroll
    for (int cf = 0; cf < 4; ++cf) { h6[cf] = t6[cf]; h7[cf] = t7[cf]; h8[cf] = t8[cf]; }
  }
  UNIT(9, 2752, h9);
  UNIT(10, 3008, h10);

  // ---- final combine ----
  float qtp[4] = {0.f, 0.f, 0.f, 0.f};
  #pragma unroll
  for (int cf = 0; cf < 4; ++cf) {
    int e = cf * 16 + l16;
    float b6 = hw1b2[e], b7 = hw1b2[64 + e], b8 = hw1b2[128 + e];
    float b9 = hb1b2[e], b10 = hw2b2[e];
    #pragma unroll
    for (int i = 0; i < 4; ++i) {
      float hv = gq[0][i] * fabsf(h6[cf][i] + b6)
               + gq[1][i] * fabsf(h7[cf][i] + b7)
               + gq[2][i] * fabsf(h8[cf][i] + b8)
               + h9[cf][i] + b9;
      qtp[i] += eluf(hv) * fabsf(h10[cf][i] + b10);
    }
  }
  #pragma unroll
  for (int i = 0; i < 4; ++i) {
    GRED(qtp[i]);
    if (l16 == 0) out[r4 + i] = qtp[i] + dotn[3][i] + hb2b2[0];
  }
#undef UNIT
#undef GRED
}

extern "C" void kernel_launch(void* const* d_in, const int* in_sizes, int n_in,
                              void* d_out, int out_size, void* d_ws, size_t ws_size,
                              hipStream_t stream) {
  const float* qvals  = (const float*)d_in[0];
  const float* states = (const float*)d_in[1];
  const float* gw1W1 = (const float*)d_in[2];
  const float* gw1b1 = (const float*)d_in[3];
  const float* gw1W2 = (const float*)d_in[4];
  const float* gw1b2 = (const float*)d_in[5];
  const float* gb1W1 = (const float*)d_in[6];
  const float* gb1b1 = (const float*)d_in[7];
  const float* gb1W2 = (const float*)d_in[8];
  const float* gb1b2 = (const float*)d_in[9];
  const float* gw2W1 = (const float*)d_in[10];
  const float* gw2b1 = (const float*)d_in[11];
  const float* gw2W2 = (const float*)d_in[12];
  const float* gw2b2 = (const float*)d_in[13];
  const float* gb2W1 = (const float*)d_in[14];
  const float* gb2b1 = (const float*)d_in[15];
  const float* gb2W2 = (const float*)d_in[16];
  const float* gb2b2 = (const float*)d_in[17];
  const float* hw1W1 = (const float*)d_in[18];
  const float* hw1b1 = (const float*)d_in[19];
  const float* hw1W2 = (const float*)d_in[20];
  const float* hw1b2 = (const float*)d_in[21];
  const float* hb1W1 = (const float*)d_in[22];
  const float* hb1b1 = (const float*)d_in[23];
  const float* hb1W2 = (const float*)d_in[24];
  const float* hb1b2 = (const float*)d_in[25];
  const float* hw2W1 = (const float*)d_in[26];
  const float* hw2b1 = (const float*)d_in[27];
  const float* hw2W2 = (const float*)d_in[28];
  const float* hw2b2 = (const float*)d_in[29];
  const float* hb2W1 = (const float*)d_in[30];
  const float* hb2b1 = (const float*)d_in[31];
  const float* hb2W2 = (const float*)d_in[32];
  const float* hb2b2 = (const float*)d_in[33];
  float* out = (float*)d_out;

  char* p = (char*)d_ws;
  u16* A       = (u16*)p;   p += (size_t)NN * KP * 2;     // 41.9 MB; reused as qw1acc after gemm1
  u16* BT      = (u16*)p;   p += (size_t)NC * KP * 2;
  u16* act     = (u16*)p;   p += (size_t)NN * NC * 2;
  u16* w2tw1   = (u16*)p;   p += (size_t)5760 * NH * 2;
  u16* w2ts    = (u16*)p;   p += (size_t)12 * 16384 * 2;
  float* bias  = (float*)p; p += (size_t)NC * 4;
  int* grps    = (int*)p;   p += (size_t)NB * NA * 4;
  int* gcnt    = (int*)p;   p += (size_t)NB * 4 * 4;
  float* qw1acc = (float*)A;   // NN*192*4 = 6.3 MB < 41.9 MB; A dead after gemm1

  pack_all_k<<<15217, 256, 0, stream>>>(states,
                                        gw1W1, gw1b1, gb1W1, gb1b1, gw2W1, gw2b1, gb2W1, gb2b1,
                                        hw1W1, hw1b1, hb1W1, hb1b1, hw2W1, hw2b1, hb2W1, hb2b1,
                                        gw1W2, gb1W2, gw2W2, hw1W2, hb1W2, hw2W2, gb2W2, hb2W2,
                                        A, BT, bias, w2tw1, w2ts, grps, gcnt);
  gemm1_k<<<416, 512, 0, stream>>>(A, BT, bias, act);
  c1a_k<<<dim3(256, 3), 128, 0, stream>>>(act, qvals, grps, gcnt, w2tw1, gw1b2, qw1acc);
  c1bc2_k<<<128, 256, 0, stream>>>(act, qw1acc, w2ts, gb1b2, gw2b2, hw1b2, hb1b2, hw2b2,
                                   gb2b2, hb2b2, out);
}

// Round 15
// 235.735 us; speedup vs baseline: 1.2496x; 1.2496x over previous
//
#include <hip/hip_runtime.h>

typedef unsigned short u16;
typedef __bf16 bf16x8 __attribute__((ext_vector_type(8)));
typedef float f32x4 __attribute__((ext_vector_type(4)));
typedef unsigned short u16x8 __attribute__((ext_vector_type(8)));

#define NB 64
#define NT 128
#define NA 30
#define NG 3
#define NE 64
#define NH 256
#define NN 8192     // B*T
#define SD 2520
#define KP 2560     // K padded to mult of 64
#define NC 3328     // concat first-layer cols = 13*256
#define NKT 40      // K tiles of 64
#define NITER 20    // 2 K-tiles per iteration

__device__ __forceinline__ u16 f2bf(float f) {
  union { float f; unsigned u; } c; c.f = f;
  unsigned u = c.u + 0x7FFFu + ((c.u >> 16) & 1u);
  return (u16)(u >> 16);
}
__device__ __forceinline__ float bf2f(u16 h) {
  union { unsigned u; float f; } c; c.u = ((unsigned)h) << 16;
  return c.f;
}
__device__ __forceinline__ float eluf(float x) { return x > 0.f ? x : expm1f(x); }

__device__ __forceinline__ void gload16(const u16* g, u16* l) {
  __builtin_amdgcn_global_load_lds((const __attribute__((address_space(1))) void*)g,
                                   (__attribute__((address_space(3))) void*)l, 16, 0, 0);
}

__device__ __forceinline__ float wredsum(float v) {
  #pragma unroll
  for (int d = 32; d > 0; d >>= 1) v += __shfl_xor(v, d, 64);
  return v;
}

// ---------------- merged pack kernel: A + BT + w2tw1(frag) + w2ts(frag) + grps(sorted)+cnt ----------------
__global__ __launch_bounds__(256) void pack_all_k(
    const float* __restrict__ states,
    const float* __restrict__ gw1W1, const float* __restrict__ gw1b1,
    const float* __restrict__ gb1W1, const float* __restrict__ gb1b1,
    const float* __restrict__ gw2W1, const float* __restrict__ gw2b1,
    const float* __restrict__ gb2W1, const float* __restrict__ gb2b1,
    const float* __restrict__ hw1W1, const float* __restrict__ hw1b1,
    const float* __restrict__ hb1W1, const float* __restrict__ hb1b1,
    const float* __restrict__ hw2W1, const float* __restrict__ hw2b1,
    const float* __restrict__ hb2W1, const float* __restrict__ hb2b1,
    const float* __restrict__ gw1W2, const float* __restrict__ gb1W2,
    const float* __restrict__ gw2W2, const float* __restrict__ hw1W2,
    const float* __restrict__ hb1W2, const float* __restrict__ hw2W2,
    u16* __restrict__ A, u16* __restrict__ BT, float* __restrict__ bias,
    u16* __restrict__ w2tw1, u16* __restrict__ w2ts,
    int* __restrict__ grps, int* __restrict__ gcnt) {
  int bid = blockIdx.x;
  if (bid < 10240) {
    // ---- pack A: bf16[n][KP] from states f32 ----
    int tid = bid * 256 + threadIdx.x;            // 8192*320 exact
    int n = tid / 320, kq = tid - n * 320;
    int k = kq * 8;
    u16x8 v;
    if (k < SD) {
      const float4* p = reinterpret_cast<const float4*>(states + (size_t)n * SD + k);
      float4 x0 = p[0], x1 = p[1];
      v[0]=f2bf(x0.x); v[1]=f2bf(x0.y); v[2]=f2bf(x0.z); v[3]=f2bf(x0.w);
      v[4]=f2bf(x1.x); v[5]=f2bf(x1.y); v[6]=f2bf(x1.z); v[7]=f2bf(x1.w);
    } else {
      v[0]=0;v[1]=0;v[2]=0;v[3]=0;v[4]=0;v[5]=0;v[6]=0;v[7]=0;
    }
    *reinterpret_cast<u16x8*>(A + (size_t)n * KP + k) = v;
  } else if (bid < 14400) {
    // ---- pack BT (+bias) ----
    int tid = (bid - 10240) * 256 + threadIdx.x;  // 320*3328 exact
    int kq = tid / NC, j = tid - kq * NC;
    const float* W; const float* bsrc; size_t cbase; int stride; int q;
    if (j < 768)        { q=j;      int g=q>>8; W=gw1W1; cbase=(size_t)g*SD*NH + (q&255); stride=NH; bsrc=gw1b1; }
    else if (j < 1536)  { q=j-768;  int g=q>>8; W=gb1W1; cbase=(size_t)g*SD*NH + (q&255); stride=NH; bsrc=gb1b1; }
    else if (j < 2304)  { q=j-1536; int g=q>>8; W=gw2W1; cbase=(size_t)g*SD*NH + (q&255); stride=NH; bsrc=gw2b1; }
    else if (j < 2496)  { q=j-2304; int g=q>>6; W=gb2W1; cbase=(size_t)g*SD*NE + (q&63);  stride=NE; bsrc=gb2b1; }
    else if (j < 2752)  { q=j-2496; W=hw1W1; cbase=q; stride=NH; bsrc=hw1b1; }
    else if (j < 3008)  { q=j-2752; W=hb1W1; cbase=q; stride=NH; bsrc=hb1b1; }
    else if (j < 3264)  { q=j-3008; W=hw2W1; cbase=q; stride=NH; bsrc=hw2b1; }
    else                { q=j-3264; W=hb2W1; cbase=q; stride=NE; bsrc=hb2b1; }
    int k = kq * 8;
    u16x8 v;
    #pragma unroll
    for (int i = 0; i < 8; ++i) {
      int d = k + i;
      v[i] = (d < SD) ? f2bf(W[cbase + (size_t)d * stride]) : (u16)0;
    }
    *reinterpret_cast<u16x8*>(BT + (size_t)j * KP + k) = v;
    if (kq == 0) bias[j] = bsrc[q];
  } else if (bid < 15120) {
    // ---- pack w2tw1 in fragment-major order (90 slabs x 2048 threads) ----
    int tid = (bid - 14400) * 256 + threadIdx.x;  // 184320 exact
    int lane = tid & 63, cf = (tid >> 6) & 3, ks = (tid >> 8) & 7, slab = tid >> 11;
    int g = slab / 30, a = slab - g * 30;
    int e = cf * 16 + (lane & 15);
    int h0 = ks * 32 + (lane >> 4) * 8;
    const float* src = gw1W2 + (size_t)g * (NH * 1920) + (size_t)h0 * 1920 + a * 64 + e;
    u16x8 v;
    #pragma unroll
    for (int i = 0; i < 8; ++i) v[i] = f2bf(src[(size_t)i * 1920]);
    *reinterpret_cast<u16x8*>(w2tw1 + (size_t)tid * 8) = v;
  } else if (bid < 15208) {
    // ---- pack w2ts in fragment-major order (11 units x 2048 threads) ----
    int tid = (bid - 15120) * 256 + threadIdx.x;  // 22528 exact
    int lane = tid & 63, cf = (tid >> 6) & 3, ks = (tid >> 8) & 7, u = tid >> 11;
    int e = cf * 16 + (lane & 15);
    int h0 = ks * 32 + (lane >> 4) * 8;
    const float* src; int stride;
    if (u < 3)       { src = gb1W2 + (size_t)u * (NH*NE) + (size_t)h0 * NE + e;     stride = NE; }
    else if (u < 6)  { src = gw2W2 + (size_t)(u-3) * (NH*NE) + (size_t)h0 * NE + e; stride = NE; }
    else if (u < 9)  { src = hw1W2 + (size_t)h0 * (NG*NE) + (u-6)*64 + e;           stride = NG*NE; }
    else if (u == 9) { src = hb1W2 + (size_t)h0 * NE + e;                           stride = NE; }
    else             { src = hw2W2 + (size_t)h0 * NE + e;                           stride = NE; }
    u16x8 v;
    #pragma unroll
    for (int i = 0; i < 8; ++i) v[i] = f2bf(src[(size_t)i * stride]);
    *reinterpret_cast<u16x8*>(w2ts + (size_t)tid * 8) = v;
  } else {
    // ---- grps: per-b counting sort of agents by group; entry = a; cnt table ----
    int b = threadIdx.x;
    if (b >= NB) return;
    int gv0 = 0, gv1 = 0;
    int cnt0 = 0, cnt1 = 0, cnt2 = 0;
    #pragma unroll
    for (int a = 0; a < NA; ++a) {
      int g = 0;
      #pragma unroll
      for (int gi = 0; gi < NG; ++gi)
        if (states[(size_t)b * NT * SD + a * 32 + 29 + gi] == 1.0f) g = gi;
      if (a < 15) gv0 |= g << (2 * a); else gv1 |= g << (2 * (a - 15));
      if (g == 0) ++cnt0; else if (g == 1) ++cnt1; else ++cnt2;
    }
    gcnt[b * 4 + 0] = cnt0; gcnt[b * 4 + 1] = cnt1; gcnt[b * 4 + 2] = cnt2;
    int off0 = 0, off1 = cnt0, off2 = cnt0 + cnt1;
    #pragma unroll
    for (int a = 0; a < NA; ++a) {
      int g = (a < 15) ? ((gv0 >> (2 * a)) & 3) : ((gv1 >> (2 * (a - 15))) & 3);
      int pos;
      if (g == 0) pos = off0++; else if (g == 1) pos = off1++; else pos = off2++;
      grps[b * NA + pos] = a;
    }
  }
}

// ---------------- big concat GEMM: act = relu(A @ BT^T + bias) ----------------
// m201-style 8-phase schedule (R7, best measured): 256x256 tile, BK=64, 8 waves
// (2Mx4N), 2 dbufs x 4 half-tile slots (16 KB each) = 128 KB. vmcnt(4) at
// phases 4/8 only. Zero-conflict XOR swizzle (verified R4/R6/R7).
__global__ __launch_bounds__(512, 2) void gemm1_k(const u16* __restrict__ A, const u16* __restrict__ BT,
    const float* __restrict__ bias, u16* __restrict__ act) {
  __shared__ u16 lds[65536];          // 2 bufs x (Aa,Ab,Ba,Bb) x 16 KB = 128 KB
  int t = threadIdx.x;
  int wg = blockIdx.x;                // 416 = 32 x 13, 416 % 8 == 0
  int swz = (wg & 7) * 52 + (wg >> 3);
  int by = swz / 13, bx = swz - by * 13;
  size_t mb = (size_t)by * 256, nb = (size_t)bx * 256;
  int lane = t & 63, w = t >> 6;
  int wm = (w >> 2) * 128;            // 2 M-waves
  int wn = (w & 3) * 64;              // 4 N-waves
  int l15 = lane & 15, hi = lane >> 4;

  int srow = t >> 3;                                    // 0..63
  int scol = (((t & 7) ^ (srow & 7)) << 3);             // swizzled source col (elems)
  const u16* aS = A + (mb + srow) * KP + scol;
  const u16* bS = BT + (nb + srow) * KP + scol;

#define STGA(buf, h, kt) { \
    u16* d_ = lds + (buf) * 32768 + (h) * 8192; \
    const u16* s_ = aS + (size_t)((h) * 128) * KP + (size_t)(kt) * 64; \
    gload16(s_,                  d_ + t * 8); \
    gload16(s_ + (size_t)64 * KP, d_ + 4096 + t * 8); }
#define STGB(buf, h, kt) { \
    u16* d_ = lds + (buf) * 32768 + 16384 + (h) * 8192; \
    const u16* s_ = bS + (size_t)((h) * 128) * KP + (size_t)(kt) * 64; \
    gload16(s_,                  d_ + t * 8); \
    gload16(s_ + (size_t)64 * KP, d_ + 4096 + t * 8); }

  f32x4 acc[8][4];
  #pragma unroll
  for (int mi = 0; mi < 8; ++mi)
    #pragma unroll
    for (int ni = 0; ni < 4; ++ni) acc[mi][ni] = {0.f, 0.f, 0.f, 0.f};

  const char* A0 = (const char*)(lds) + (wm ? 16384 : 0);
  const char* B0 = (const char*)(lds) + 32768 + ((wn & 128) ? 16384 : 0);
  const char* A1 = A0 + 65536;
  const char* B1 = B0 + 65536;
  int rx = l15 & 7;
  int aBase = l15 * 128;
  int bBase = ((wn & 64) + l15) * 128;
  int slot0 = (hi ^ rx) << 4;
  int slot1 = ((4 + hi) ^ rx) << 4;

  bf16x8 afA[4][2], afB[4][2], bfA[2][2], bfB[2][2];

#define LD_AFA(Ab) { _Pragma("unroll") for (int m_ = 0; m_ < 4; ++m_) { \
    afA[m_][0] = *reinterpret_cast<const bf16x8*>((Ab) + aBase + m_ * 2048 + slot0); \
    afA[m_][1] = *reinterpret_cast<const bf16x8*>((Ab) + aBase + m_ * 2048 + slot1); } }
#define LD_AFB(Ab) { _Pragma("unroll") for (int m_ = 0; m_ < 4; ++m_) { \
    afB[m_][0] = *reinterpret_cast<const bf16x8*>((Ab) + aBase + (4 + m_) * 2048 + slot0); \
    afB[m_][1] = *reinterpret_cast<const bf16x8*>((Ab) + aBase + (4 + m_) * 2048 + slot1); } }
#define LD_BFA(Bb) { _Pragma("unroll") for (int n_ = 0; n_ < 2; ++n_) { \
    bfA[n_][0] = *reinterpret_cast<const bf16x8*>((Bb) + bBase + n_ * 2048 + slot0); \
    bfA[n_][1] = *reinterpret_cast<const bf16x8*>((Bb) + bBase + n_ * 2048 + slot1); } }
#define LD_BFB(Bb) { _Pragma("unroll") for (int n_ = 0; n_ < 2; ++n_) { \
    bfB[n_][0] = *reinterpret_cast<const bf16x8*>((Bb) + bBase + (2 + n_) * 2048 + slot0); \
    bfB[n_][1] = *reinterpret_cast<const bf16x8*>((Bb) + bBase + (2 + n_) * 2048 + slot1); } }
#define MM_Q(AF, BF, MO, NO) { _Pragma("unroll") for (int m_ = 0; m_ < 4; ++m_) \
    _Pragma("unroll") for (int n_ = 0; n_ < 2; ++n_) { \
      acc[(MO)+m_][(NO)+n_] = __builtin_amdgcn_mfma_f32_16x16x32_bf16(AF[m_][0], BF[n_][0], acc[(MO)+m_][(NO)+n_], 0, 0, 0); \
      acc[(MO)+m_][(NO)+n_] = __builtin_amdgcn_mfma_f32_16x16x32_bf16(AF[m_][1], BF[n_][1], acc[(MO)+m_][(NO)+n_], 0, 0, 0); } }
#define SYNC_IN  __builtin_amdgcn_s_barrier(); \
                 asm volatile("s_waitcnt lgkmcnt(0)" ::: "memory"); \
                 __builtin_amdgcn_sched_barrier(0); \
                 __builtin_amdgcn_s_setprio(1);
#define SYNC_OUT __builtin_amdgcn_s_setprio(0); \
                 __builtin_amdgcn_s_barrier(); \
                 asm volatile("" ::: "memory");

  STGA(0, 0, 0); STGA(0, 1, 0); STGB(0, 0, 0); STGB(0, 1, 0);
  STGB(1, 0, 1); STGB(1, 1, 1);
  asm volatile("s_waitcnt vmcnt(4)" ::: "memory");
  __builtin_amdgcn_s_barrier();
  asm volatile("" ::: "memory");

  for (int it = 0; it < NITER; ++it) {
    int k1 = 2 * it + 1;
    bool t2 = (2 * it + 2 < NKT), t3 = (2 * it + 3 < NKT);
    LD_AFA(A0); LD_BFA(B0);
    STGA(1, 0, k1);
    SYNC_IN; MM_Q(afA, bfA, 0, 0); SYNC_OUT;
    LD_BFB(B0);
    STGA(1, 1, k1);
    SYNC_IN; MM_Q(afA, bfB, 0, 2); SYNC_OUT;
    LD_AFB(A0);
    if (t2) STGB(0, 0, 2 * it + 2);
    SYNC_IN; MM_Q(afB, bfB, 4, 2); SYNC_OUT;
    if (t2) STGB(0, 1, 2 * it + 2);
    __builtin_amdgcn_s_barrier();
    __builtin_amdgcn_s_setprio(1); MM_Q(afB, bfA, 4, 0); __builtin_amdgcn_s_setprio(0);
    if (it == NITER - 1) { asm volatile("s_waitcnt vmcnt(0)" ::: "memory"); }
    else                 { asm volatile("s_waitcnt vmcnt(4)" ::: "memory"); }
    __builtin_amdgcn_s_barrier();
    asm volatile("" ::: "memory");
    LD_AFA(A1); LD_BFA(B1);
    if (t2) STGA(0, 0, 2 * it + 2);
    SYNC_IN; MM_Q(afA, bfA, 0, 0); SYNC_OUT;
    LD_BFB(B1);
    if (t2) STGA(0, 1, 2 * it + 2);
    SYNC_IN; MM_Q(afA, bfB, 0, 2); SYNC_OUT;
    LD_AFB(A1);
    if (t3) STGB(1, 0, 2 * it + 3);
    SYNC_IN; MM_Q(afB, bfB, 4, 2); SYNC_OUT;
    if (t3) STGB(1, 1, 2 * it + 3);
    __builtin_amdgcn_s_barrier();
    __builtin_amdgcn_s_setprio(1); MM_Q(afB, bfA, 4, 0); __builtin_amdgcn_s_setprio(0);
    if (t3) { asm volatile("s_waitcnt vmcnt(4)" ::: "memory"); }
    __builtin_amdgcn_s_barrier();
    asm volatile("" ::: "memory");
  }

  int r00 = (int)mb + wm + hi * 4;
  int cc0 = (int)nb + wn + l15;
  float bv0 = bias[cc0], bv1 = bias[cc0 + 16], bv2 = bias[cc0 + 32], bv3 = bias[cc0 + 48];
  #pragma unroll
  for (int mi = 0; mi < 8; ++mi) {
    #pragma unroll
    for (int i = 0; i < 4; ++i) {
      u16* dst = act + (size_t)(r00 + mi * 16 + i) * NC + cc0;
      float v0 = acc[mi][0][i] + bv0; v0 = v0 > 0.f ? v0 : 0.f;
      float v1 = acc[mi][1][i] + bv1; v1 = v1 > 0.f ? v1 : 0.f;
      float v2 = acc[mi][2][i] + bv2; v2 = v2 > 0.f ? v2 : 0.f;
      float v3 = acc[mi][3][i] + bv3; v3 = v3 > 0.f ? v3 : 0.f;
      dst[0] = f2bf(v0); dst[16] = f2bf(v1); dst[32] = f2bf(v2); dst[48] = f2bf(v3);
    }
  }
#undef STGA
#undef STGB
#undef LD_AFA
#undef LD_AFB
#undef LD_BFA
#undef LD_BFB
#undef MM_Q
#undef SYNC_IN
#undef SYNC_OUT
}

// ---------------- masked w1 second layer + q-weighted group accumulate ----------------
// one block per (32 rows, group): af loaded once, single accumulator set,
// DISJOINT qw1acc[g] slices (no partial buffers, no c2 summation).
__global__ __launch_bounds__(128) void c1a_k(const u16* __restrict__ act, const float* __restrict__ qvals,
    const int* __restrict__ grps, const int* __restrict__ gcnt, const u16* __restrict__ w2tw1,
    const float* __restrict__ gw1b2, float* __restrict__ qw1acc) {
  int t = threadIdx.x, lane = t & 63, w = t >> 6;
  int rb = blockIdx.x;                  // 256 row-blocks * 32 rows
  int g = blockIdx.y;                   // 3 groups
  int nb0 = rb * 32 + w * 16;
  int b = rb >> 2;                      // uniform b per block
  int l16 = lane & 15, lk8 = (lane >> 4) * 8;
  int cnt0 = gcnt[b * 4], cnt1 = gcnt[b * 4 + 1], cnt2 = gcnt[b * 4 + 2];
  int start = (g >= 1 ? cnt0 : 0) + (g >= 2 ? cnt1 : 0);
  int cnt = (g == 0) ? cnt0 : (g == 1) ? cnt1 : cnt2;
  float gacc[4][4];
  #pragma unroll
  for (int cf = 0; cf < 4; ++cf)
    #pragma unroll
    for (int i = 0; i < 4; ++i) gacc[cf][i] = 0.f;
  const u16* arow = act + (size_t)(nb0 + l16) * NC;
  int r4 = nb0 + (lane >> 4) * 4;
  const u16* abase = arow + g * NH;
  bf16x8 af0[4], af1[4];
  #pragma unroll
  for (int ks = 0; ks < 4; ++ks) {
    af0[ks] = *reinterpret_cast<const bf16x8*>(abase + ks * 32 + lk8);
    af1[ks] = *reinterpret_cast<const bf16x8*>(abase + (4 + ks) * 32 + lk8);
  }
  const int* sl = grps + b * NA + start;
  for (int ai = 0; ai < cnt; ++ai) {
    int a = sl[ai];
    f32x4 t4[4], u4[4];
    #pragma unroll
    for (int cf = 0; cf < 4; ++cf) { t4[cf] = {0.f,0.f,0.f,0.f}; u4[cf] = {0.f,0.f,0.f,0.f}; }
    const u16* bbase = w2tw1 + (size_t)(g * NA + a) * 16384 + lane * 8;
    #pragma unroll
    for (int ks = 0; ks < 4; ++ks) {
      #pragma unroll
      for (int cf = 0; cf < 4; ++cf) {
        bf16x8 bf0 = *reinterpret_cast<const bf16x8*>(bbase + (ks * 4 + cf) * 512);
        bf16x8 bf1 = *reinterpret_cast<const bf16x8*>(bbase + ((4 + ks) * 4 + cf) * 512);
        t4[cf] = __builtin_amdgcn_mfma_f32_16x16x32_bf16(af0[ks], bf0, t4[cf], 0, 0, 0);
        u4[cf] = __builtin_amdgcn_mfma_f32_16x16x32_bf16(af1[ks], bf1, u4[cf], 0, 0, 0);
      }
    }
    float qv[4];
    #pragma unroll
    for (int i = 0; i < 4; ++i) qv[i] = qvals[(size_t)(r4 + i) * NA + a];
    const float* bias = gw1b2 + (size_t)g * (NA * NE) + a * NE;
    #pragma unroll
    for (int cf = 0; cf < 4; ++cf) {
      float bv = bias[cf*16 + l16];
      #pragma unroll
      for (int i = 0; i < 4; ++i) gacc[cf][i] += qv[i] * fabsf(t4[cf][i] + u4[cf][i] + bv);
    }
  }
  #pragma unroll
  for (int cf = 0; cf < 4; ++cf)
    #pragma unroll
    for (int i = 0; i < 4; ++i)
      qw1acc[(size_t)(r4 + i) * 192 + g * 64 + cf * 16 + l16] = gacc[cf][i];
}

// ---------------- 11 small dense second layers (fragment-major w2ts) ----------------
__global__ __launch_bounds__(256) void c1b_k(const u16* __restrict__ act, const u16* __restrict__ w2ts,
    const float* __restrict__ gb1b2, const float* __restrict__ gw2b2, const float* __restrict__ hw1b2,
    const float* __restrict__ hb1b2, const float* __restrict__ hw2b2,
    float* __restrict__ b1s, float* __restrict__ w2s, float* __restrict__ hw1s,
    float* __restrict__ hb1s, float* __restrict__ hw2s) {
  int u = blockIdx.x, blk = blockIdx.y;
  int t = threadIdx.x, lane = t & 63, w = t >> 6;
  int nb0 = blk * 64 + w * 16;
  int l16 = lane & 15, lk8 = (lane >> 4) * 8;
  int aoff = (u < 3) ? 768 + u * 256 : (u < 6) ? 1536 + (u-3) * 256 : (u < 9) ? 2496 : (u == 9) ? 2752 : 3008;
  const float* bias; float* outp; int ostride; bool ab;
  if (u < 3)       { bias = gb1b2 + u * 64;       outp = b1s  + u * 64;     ostride = 192; ab = false; }
  else if (u < 6)  { bias = gw2b2 + (u-3) * 64;   outp = w2s  + (u-3) * 64; ostride = 192; ab = true; }
  else if (u < 9)  { bias = hw1b2 + (u-6) * 64;   outp = hw1s + (u-6) * 64; ostride = 192; ab = true; }
  else if (u == 9) { bias = hb1b2;                outp = hb1s;              ostride = 64;  ab = false; }
  else             { bias = hw2b2;                outp = hw2s;              ostride = 64;  ab = true; }
  f32x4 t4[4];
  #pragma unroll
  for (int cf = 0; cf < 4; ++cf) t4[cf] = {0.f, 0.f, 0.f, 0.f};
  const u16* arow = act + (size_t)(nb0 + l16) * NC + aoff;
  const u16* bbase = w2ts + (size_t)u * 16384 + lane * 8;
  #pragma unroll
  for (int ks = 0; ks < 8; ++ks) {
    bf16x8 af = *reinterpret_cast<const bf16x8*>(arow + ks * 32 + lk8);
    #pragma unroll
    for (int cf = 0; cf < 4; ++cf) {
      bf16x8 bf = *reinterpret_cast<const bf16x8*>(bbase + (ks * 4 + cf) * 512);
      t4[cf] = __builtin_amdgcn_mfma_f32_16x16x32_bf16(af, bf, t4[cf], 0, 0, 0);
    }
  }
  int r4 = nb0 + (lane >> 4) * 4;
  #pragma unroll
  for (int cf = 0; cf < 4; ++cf) {
    float bv = bias[cf*16 + l16];
    #pragma unroll
    for (int i = 0; i < 4; ++i) {
      float v = t4[cf][i] + bv;
      if (ab) v = fabsf(v);
      outp[(size_t)(r4 + i) * ostride + cf * 16 + l16] = v;
    }
  }
}

// ---------------- final per-token combine: one wave per token ----------------
__global__ __launch_bounds__(256) void c2_k(const u16* __restrict__ act,
    const float* __restrict__ qw1acc, const float* __restrict__ b1s, const float* __restrict__ w2s,
    const float* __restrict__ hw1s, const float* __restrict__ hb1s, const float* __restrict__ hw2s,
    const float* __restrict__ gb2W2, const float* __restrict__ gb2b2,
    const float* __restrict__ hb2W2, const float* __restrict__ hb2b2,
    float* __restrict__ out) {
  int gtid = blockIdx.x * 256 + threadIdx.x;   // 2048 blocks x 4 waves = 8192 tokens
  int n = gtid >> 6, e = gtid & 63;
  const u16* an = act + (size_t)n * NC;
  const float* qn = qw1acc + (size_t)n * 192;
  float q0 = qn[e], q1 = qn[64 + e], q2 = qn[128 + e];
  const float* b1n = b1s + (size_t)n * 192;
  const float* w2n = w2s + (size_t)n * 192;
  float s0 = bf2f(an[2304 + e]) * gb2W2[e]       + eluf(q0 + b1n[e])       * w2n[e];
  float s1 = bf2f(an[2368 + e]) * gb2W2[64 + e]  + eluf(q1 + b1n[64 + e])  * w2n[64 + e];
  float s2 = bf2f(an[2432 + e]) * gb2W2[128 + e] + eluf(q2 + b1n[128 + e]) * w2n[128 + e];
  float sh = bf2f(an[3264 + e]) * hb2W2[e];
  float gq0 = wredsum(s0) + gb2b2[0];
  float gq1 = wredsum(s1) + gb2b2[1];
  float gq2 = wredsum(s2) + gb2b2[2];
  float hb2v = wredsum(sh) + hb2b2[0];
  const float* hw1n = hw1s + (size_t)n * 192;
  float hv = gq0 * hw1n[e] + gq1 * hw1n[64 + e] + gq2 * hw1n[128 + e] + hb1s[(size_t)n * 64 + e];
  float c = eluf(hv) * hw2s[(size_t)n * 64 + e];
  float qt = wredsum(c) + hb2v;
  if (e == 0) out[n] = qt;
}

extern "C" void kernel_launch(void* const* d_in, const int* in_sizes, int n_in,
                              void* d_out, int out_size, void* d_ws, size_t ws_size,
                              hipStream_t stream) {
  const float* qvals  = (const float*)d_in[0];
  const float* states = (const float*)d_in[1];
  const float* gw1W1 = (const float*)d_in[2];
  const float* gw1b1 = (const float*)d_in[3];
  const float* gw1W2 = (const float*)d_in[4];
  const float* gw1b2 = (const float*)d_in[5];
  const float* gb1W1 = (const float*)d_in[6];
  const float* gb1b1 = (const float*)d_in[7];
  const float* gb1W2 = (const float*)d_in[8];
  const float* gb1b2 = (const float*)d_in[9];
  const float* gw2W1 = (const float*)d_in[10];
  const float* gw2b1 = (const float*)d_in[11];
  const float* gw2W2 = (const float*)d_in[12];
  const float* gw2b2 = (const float*)d_in[13];
  const float* gb2W1 = (const float*)d_in[14];
  const float* gb2b1 = (const float*)d_in[15];
  const float* gb2W2 = (const float*)d_in[16];
  const float* gb2b2 = (const float*)d_in[17];
  const float* hw1W1 = (const float*)d_in[18];
  const float* hw1b1 = (const float*)d_in[19];
  const float* hw1W2 = (const float*)d_in[20];
  const float* hw1b2 = (const float*)d_in[21];
  const float* hb1W1 = (const float*)d_in[22];
  const float* hb1b1 = (const float*)d_in[23];
  const float* hb1W2 = (const float*)d_in[24];
  const float* hb1b2 = (const float*)d_in[25];
  const float* hw2W1 = (const float*)d_in[26];
  const float* hw2b1 = (const float*)d_in[27];
  const float* hw2W2 = (const float*)d_in[28];
  const float* hw2b2 = (const float*)d_in[29];
  const float* hb2W1 = (const float*)d_in[30];
  const float* hb2b1 = (const float*)d_in[31];
  const float* hb2W2 = (const float*)d_in[32];
  const float* hb2b2 = (const float*)d_in[33];
  float* out = (float*)d_out;

  char* p = (char*)d_ws;
  u16* A       = (u16*)p;   p += (size_t)NN * KP * 2;     // 41.9 MB; reused as qw1acc after gemm1
  u16* BT      = (u16*)p;   p += (size_t)NC * KP * 2;
  u16* act     = (u16*)p;   p += (size_t)NN * NC * 2;
  u16* w2tw1   = (u16*)p;   p += (size_t)5760 * NH * 2;
  u16* w2ts    = (u16*)p;   p += (size_t)704 * NH * 2;
  float* bias  = (float*)p; p += (size_t)NC * 4;
  int* grps    = (int*)p;   p += (size_t)NB * NA * 4;
  int* gcnt    = (int*)p;   p += (size_t)NB * 4 * 4;
  float* b1s   = (float*)p; p += (size_t)NN * 192 * 4;
  float* w2s   = (float*)p; p += (size_t)NN * 192 * 4;
  float* hw1s  = (float*)p; p += (size_t)NN * 192 * 4;
  float* hb1s  = (float*)p; p += (size_t)NN * 64 * 4;
  float* hw2s  = (float*)p; p += (size_t)NN * 64 * 4;
  float* qw1acc = (float*)A;   // NN*192*4 = 6.3 MB < 41.9 MB; A dead after gemm1

  pack_all_k<<<15209, 256, 0, stream>>>(states,
                                        gw1W1, gw1b1, gb1W1, gb1b1, gw2W1, gw2b1, gb2W1, gb2b1,
                                        hw1W1, hw1b1, hb1W1, hb1b1, hw2W1, hw2b1, hb2W1, hb2b1,
                                        gw1W2, gb1W2, gw2W2, hw1W2, hb1W2, hw2W2,
                                        A, BT, bias, w2tw1, w2ts, grps, gcnt);
  gemm1_k<<<416, 512, 0, stream>>>(A, BT, bias, act);
  c1a_k<<<dim3(256, 3), 128, 0, stream>>>(act, qvals, grps, gcnt, w2tw1, gw1b2, qw1acc);
  c1b_k<<<dim3(11, 128), 256, 0, stream>>>(act, w2ts, gb1b2, gw2b2, hw1b2, hb1b2, hw2b2,
                                           b1s, w2s, hw1s, hb1s, hw2s);
  c2_k<<<2048, 256, 0, stream>>>(act, qw1acc, b1s, w2s, hw1s, hb1s, hw2s,
                                 gb2W2, gb2b2, hb2W2, hb2b2, out);
}